// Round 10
// baseline (248.884 us; speedup 1.0000x reference)
//
#include <hip/hip_runtime.h>

#define LPOS 256
#define CCH 20
#define BB 4096
#define LC 5120   // LPOS*CCH

// seqC layout: uint2[32][4096] — entry (mw, b) holds bytes s(b, l=8mw..8mw+7).

// ---------------- Kernel 1: seq extraction + linear term -------------------
__global__ __launch_bounds__(256) void k_prepare(
    const float* __restrict__ x_lc, const float* __restrict__ theta_0,
    const float* __restrict__ theta_lc, unsigned char* __restrict__ seqC,
    float* __restrict__ out)
{
    const int b = blockIdx.x;
    const int l = threadIdx.x;
    const float* xp = x_lc + (size_t)b * LC + (size_t)l * CCH;
    const float4* xp4 = reinterpret_cast<const float4*>(xp);
    float v[CCH];
#pragma unroll
    for (int q = 0; q < 5; ++q) {
        float4 t = xp4[q];
        v[q * 4 + 0] = t.x; v[q * 4 + 1] = t.y;
        v[q * 4 + 2] = t.z; v[q * 4 + 3] = t.w;
    }
    int s = 0; float best = v[0];
#pragma unroll
    for (int c = 1; c < CCH; ++c) { if (v[c] > best) { best = v[c]; s = c; } }

    seqC[((size_t)(l >> 3) * BB + b) * 8 + (l & 7)] = (unsigned char)s;

    float lin = theta_lc[l * CCH + s];
#pragma unroll
    for (int off = 32; off > 0; off >>= 1) lin += __shfl_down(lin, off, 64);
    __shared__ float partial[4];
    const int wave = threadIdx.x >> 6;
    const int lane = threadIdx.x & 63;
    if (lane == 0) partial[wave] = lin;
    __syncthreads();
    if (threadIdx.x == 0)
        out[b] = theta_0[0] + partial[0] + partial[1] + partial[2] + partial[3];
}

// ---------------- Kernel 2: masked pairwise quadratic form -----------------
// quad[b] = sum_{l1<l2} Theta[l1,s1,l2,s2]. Inverted decomposition over a
// FLAT chunk list: all (l1, m) 8-wide l2-chunks, sorted by l1, total
// 4192 = 1048 x 4. Block k owns chunks 4k..4k+3 (exactly uniform work).
// Per chunk: stage 8x20x20 f32 table once (global_load_lds, 13 segs) into a
// DOUBLE-BUFFERED LDS table, gather all 4096 batches (thread t: batches
// i*512+t, i<8), one barrier per chunk. Partial rows -> part (no atomics).
#define QT 512
#define NMC 32                // 8-wide chunks per row
#define NQUADS 800            // 3200 f32 / 4
#define SEGS 13               // 13 x 1KB wave segments (last 1/4 pad)
#define TBLP (SEGS * 256)     // 3328 f32 (13312 B)
#define NCHT 4192             // total chunks
#define NBLK (NCHT / 4)       // 1048

template <int MODE>
__global__ __launch_bounds__(QT, 8) void k_quad(
    const float* __restrict__ Theta,          // (5120, 5120) f32 row-major
    const uint2* __restrict__ seqC,           // [32][4096]
    float* __restrict__ part,                 // [NBLK][4096] (MODE 0)
    float* __restrict__ out)                  // (MODE 1)
{
    __shared__ float Tl[2 * TBLP];   // 26.6 KB -> 4 blocks/CU

    const int blk = blockIdx.x;
    const int tid = threadIdx.x;
    const int wave = tid >> 6;
    const int lane = tid & 63;

    // ---- locate this block's 4 chunks in the flat list (scalar walk) ----
    int cl1[4], cm[4], cjl[4];
    {
        int T = blk * 4, l1 = 0;
        for (; l1 < 255; ++l1) {
            const int cnt = NMC - ((l1 + 1) >> 3);
            if (T < cnt) break;
            T -= cnt;
        }
        int m = ((l1 + 1) >> 3) + T;
#pragma unroll
        for (int d = 0; d < 4; ++d) {
            cl1[d] = l1; cm[d] = m;
            cjl[d] = (m == ((l1 + 1) >> 3)) ? ((l1 + 1) & 7) : 0;
            ++m;
            if (m == NMC) { ++l1; m = (l1 + 1) >> 3; }
        }
    }

    // Stage chunk (l1, m) into buffer dst: quad u = seg*64+lane -> elems
    // 4u..4u+3; r = u/5 (= j*20+s1), cc = u%5 -> Theta row l1*20+s1,
    // cols (8m+j)*20 + 4cc..+3. u>799 clamped (lands in LDS pad).
    auto stage = [&](int l1, int m, int dst) {
#pragma unroll
        for (int k = 0; k < 2; ++k) {
            const int seg = wave + 8 * k;
            if (seg < SEGS) {
                const int u0 = seg * 64 + lane;
                const int u = (u0 < NQUADS) ? u0 : (NQUADS - 1);
                const int r = u / 5, cc = u - r * 5;
                const int j = r / CCH, s1 = r - j * CCH;
                const float* gp = Theta + (size_t)(l1 * CCH + s1) * LC
                                        + (m * 8 + j) * CCH + cc * 4;
                float* lp = Tl + dst * TBLP + seg * 256;
                __builtin_amdgcn_global_load_lds(
                    (const __attribute__((address_space(1))) void*)gp,
                    (__attribute__((address_space(3))) void*)lp, 16, 0, 0);
            }
        }
    };
    // base[i] = s1(b_i, l1) * 20 from byte (l1&7) of seqC[l1>>3][b_i]
    auto loadbase = [&](int l1, int* basev) {
        const int mw = l1 >> 3;
        const int wsel = (l1 >> 2) & 1;
        const int sh = (l1 & 3) * 8;
#pragma unroll
        for (int i = 0; i < 8; ++i) {
            const uint2 u = seqC[(size_t)mw * BB + i * QT + tid];
            const unsigned w = wsel ? u.y : u.x;
            basev[i] = (int)((w >> sh) & 0xFFu) * CCH;
        }
    };

    float acc[8];
#pragma unroll
    for (int i = 0; i < 8; ++i) acc[i] = 0.f;

    int basev[8];
    uint2 squ[8];

    // prologue: stage chunk 0 -> buf 0; its bases + seq words
    stage(cl1[0], cm[0], 0);
    loadbase(cl1[0], basev);
#pragma unroll
    for (int i = 0; i < 8; ++i)
        squ[i] = seqC[(size_t)cm[0] * BB + i * QT + tid];
    __syncthreads();

#pragma unroll
    for (int d = 0; d < 4; ++d) {
        if (d < 3) stage(cl1[d + 1], cm[d + 1], (d + 1) & 1);   // async DMA
        const float* T = Tl + (d & 1) * TBLP;
        const int jl = cjl[d];
        if (jl == 0) {
#pragma unroll
            for (int i = 0; i < 8; ++i) {
                const uint2 u = squ[i];
#pragma unroll
                for (int j = 0; j < 8; ++j) {
                    const unsigned w = (j < 4) ? u.x : u.y;
                    const int s2 = (w >> ((j & 3) * 8)) & 0xFF;
                    acc[i] += T[j * 400 + basev[i] + s2];
                }
            }
        } else {            // ragged first chunk of a row (uniform jl)
#pragma unroll
            for (int i = 0; i < 8; ++i) {
                const uint2 u = squ[i];
#pragma unroll
                for (int j = 0; j < 8; ++j) {
                    const unsigned w = (j < 4) ? u.x : u.y;
                    const int s2 = (w >> ((j & 3) * 8)) & 0xFF;
                    const float v = T[j * 400 + basev[i] + s2];
                    acc[i] += (j >= jl) ? v : 0.f;
                }
            }
        }
        if (d < 3) {        // prep next chunk (overlaps barrier/drain)
            if (cl1[d + 1] != cl1[d]) loadbase(cl1[d + 1], basev);
#pragma unroll
            for (int i = 0; i < 8; ++i)
                squ[i] = seqC[(size_t)cm[d + 1] * BB + i * QT + tid];
        }
        __syncthreads();    // DMA drained + gathers done
    }

    if (MODE == 0) {
        float* row = part + (size_t)blk * BB;
#pragma unroll
        for (int i = 0; i < 8; ++i) row[i * QT + tid] = acc[i];
    } else {
#pragma unroll
        for (int i = 0; i < 8; ++i) atomicAdd(&out[i * QT + tid], acc[i]);
    }
}

// ---------------- Kernel 3: reduce partial rows into out -------------------
// grid (4, 8): x -> 256 float4 of out, y -> 131 part rows each. 8 atomics/word.
__global__ __launch_bounds__(256) void k_reduce(
    const float4* __restrict__ part4,   // [NBLK][1024]
    float* __restrict__ out)
{
    const int b4 = blockIdx.x * 256 + threadIdx.x;   // < 1024
    const int r0 = blockIdx.y * 131;
    const int r1 = min(r0 + 131, NBLK);
    float4 a = make_float4(0.f, 0.f, 0.f, 0.f);
    for (int r = r0; r < r1; ++r) {
        const float4 p = part4[(size_t)r * 1024 + b4];
        a.x += p.x; a.y += p.y; a.z += p.z; a.w += p.w;
    }
    atomicAdd(&out[b4 * 4 + 0], a.x);
    atomicAdd(&out[b4 * 4 + 1], a.y);
    atomicAdd(&out[b4 * 4 + 2], a.z);
    atomicAdd(&out[b4 * 4 + 3], a.w);
}

extern "C" void kernel_launch(void* const* d_in, const int* in_sizes, int n_in,
                              void* d_out, int out_size, void* d_ws, size_t ws_size,
                              hipStream_t stream) {
    const float* x_lc       = (const float*)d_in[0];
    const float* theta_0    = (const float*)d_in[1];
    const float* theta_lc   = (const float*)d_in[2];
    const float* theta_lclc = (const float*)d_in[3];
    // d_in[4] = mask (bool) — implicit: we only iterate l2 > l1.
    float* out = (float*)d_out;

    unsigned char* seqC = (unsigned char*)d_ws;            // 1 MB
    float* part = (float*)((char*)d_ws + (1 << 20));       // 17.2 MB
    const size_t need = (1 << 20) + (size_t)NBLK * BB * 4;

    k_prepare<<<dim3(BB), dim3(256), 0, stream>>>(x_lc, theta_0, theta_lc, seqC, out);
    if (ws_size >= need) {
        k_quad<0><<<dim3(NBLK), dim3(QT), 0, stream>>>(
            theta_lclc, (const uint2*)seqC, part, out);
        k_reduce<<<dim3(4, 8), dim3(256), 0, stream>>>(
            (const float4*)part, out);
    } else {
        k_quad<1><<<dim3(NBLK), dim3(QT), 0, stream>>>(
            theta_lclc, (const uint2*)seqC, part, out);
    }
}

// Round 11
// 92.954 us; speedup vs baseline: 2.6775x; 2.6775x over previous
//
#include <hip/hip_runtime.h>

#define LPOS 256
#define CCH 20
#define BB 4096
#define LC 5120   // LPOS*CCH

// seqC layout: uint2[32][4096] — entry (mw, b) holds bytes s(b, l=8mw..8mw+7).

// ---------------- Kernel 1: seq extraction + linear term -------------------
__global__ __launch_bounds__(256) void k_prepare(
    const float* __restrict__ x_lc, const float* __restrict__ theta_0,
    const float* __restrict__ theta_lc, unsigned char* __restrict__ seqC,
    float* __restrict__ out)
{
    const int b = blockIdx.x;
    const int l = threadIdx.x;
    const float* xp = x_lc + (size_t)b * LC + (size_t)l * CCH;
    const float4* xp4 = reinterpret_cast<const float4*>(xp);
    float v[CCH];
#pragma unroll
    for (int q = 0; q < 5; ++q) {
        float4 t = xp4[q];
        v[q * 4 + 0] = t.x; v[q * 4 + 1] = t.y;
        v[q * 4 + 2] = t.z; v[q * 4 + 3] = t.w;
    }
    int s = 0; float best = v[0];
#pragma unroll
    for (int c = 1; c < CCH; ++c) { if (v[c] > best) { best = v[c]; s = c; } }

    seqC[((size_t)(l >> 3) * BB + b) * 8 + (l & 7)] = (unsigned char)s;

    float lin = theta_lc[l * CCH + s];
#pragma unroll
    for (int off = 32; off > 0; off >>= 1) lin += __shfl_down(lin, off, 64);
    __shared__ float partial[4];
    const int wave = threadIdx.x >> 6;
    const int lane = threadIdx.x & 63;
    if (lane == 0) partial[wave] = lin;
    __syncthreads();
    if (threadIdx.x == 0)
        out[b] = theta_0[0] + partial[0] + partial[1] + partial[2] + partial[3];
}

// ---------------- Kernel 2: masked pairwise quadratic form -----------------
// quad[b] = sum_{l1<l2} Theta[l1,s1,l2,s2]. Inverted decomposition over a
// FLAT chunk list (4192 8-wide l2-chunks = 1048 blocks x 4, exactly uniform).
// Per chunk: table (8x20x20 f32) staged ONCE via global_load_lds into a
// DOUBLE-BUFFERED LDS table (dbuf costs no VGPRs: DMA has no reg dest);
// stage(d+1) issued before gathering chunk d, ONE barrier per chunk.
// LOW register pressure: seq words loaded inline (one uint2 live), basev
// recomputed only on l1 change (round-10 spill lesson: no prefetch arrays).
#define QT 512
#define NMC 32                // 8-wide chunks per row
#define NQUADS 800            // 3200 f32 / 4
#define SEGS 13               // 13 x 1KB wave segments (last 1/4 pad)
#define TBLP (SEGS * 256)     // 3328 f32 (13312 B)
#define NCHT 4192             // total chunks
#define NBLK (NCHT / 4)       // 1048

template <int MODE>
__global__ __launch_bounds__(QT, 8) void k_quad(
    const float* __restrict__ Theta,          // (5120, 5120) f32 row-major
    const uint2* __restrict__ seqC,           // [32][4096]
    float* __restrict__ part,                 // [NBLK][4096] (MODE 0)
    float* __restrict__ out)                  // (MODE 1)
{
    __shared__ float Tl[2 * TBLP];   // 26.6 KB -> 4 blocks/CU (wave-capped)

    const int blk = blockIdx.x;
    const int tid = threadIdx.x;
    const int wave = tid >> 6;
    const int lane = tid & 63;

    // ---- locate this block's 4 chunks in the flat list (scalar walk) ----
    int cl1[4], cm[4], cjl[4];
    {
        int T = blk * 4, l1 = 0;
        for (; l1 < 255; ++l1) {
            const int cnt = NMC - ((l1 + 1) >> 3);
            if (T < cnt) break;
            T -= cnt;
        }
        int m = ((l1 + 1) >> 3) + T;
#pragma unroll
        for (int d = 0; d < 4; ++d) {
            cl1[d] = l1; cm[d] = m;
            cjl[d] = (m == ((l1 + 1) >> 3)) ? ((l1 + 1) & 7) : 0;
            ++m;
            if (m == NMC) { ++l1; m = (l1 + 1) >> 3; }
        }
    }

    // Stage chunk (l1, m) into buffer dst: quad u = seg*64+lane -> elems
    // 4u..4u+3; r = u/5 (= j*20+s1), cc = u%5 -> Theta row l1*20+s1,
    // cols (8m+j)*20 + 4cc..+3. u>799 clamped (lands in LDS pad).
    auto stage = [&](int l1, int m, int dst) {
#pragma unroll
        for (int k = 0; k < 2; ++k) {
            const int seg = wave + 8 * k;
            if (seg < SEGS) {
                const int u0 = seg * 64 + lane;
                const int u = (u0 < NQUADS) ? u0 : (NQUADS - 1);
                const int r = u / 5, cc = u - r * 5;
                const int j = r / CCH, s1 = r - j * CCH;
                const float* gp = Theta + (size_t)(l1 * CCH + s1) * LC
                                        + (m * 8 + j) * CCH + cc * 4;
                float* lp = Tl + dst * TBLP + seg * 256;
                __builtin_amdgcn_global_load_lds(
                    (const __attribute__((address_space(1))) void*)gp,
                    (__attribute__((address_space(3))) void*)lp, 16, 0, 0);
            }
        }
    };
    // basev[i] = s1(b_i, l1) * 20 from byte (l1&7) of seqC[l1>>3][b_i]
    int basev[8];
    auto loadbase = [&](int l1) {
        const int mw = l1 >> 3;
        const int wsel = (l1 >> 2) & 1;
        const int sh = (l1 & 3) * 8;
#pragma unroll
        for (int i = 0; i < 8; ++i) {
            const uint2 u = seqC[(size_t)mw * BB + i * QT + tid];
            const unsigned w = wsel ? u.y : u.x;
            basev[i] = (int)((w >> sh) & 0xFFu) * CCH;
        }
    };

    float acc[8];
#pragma unroll
    for (int i = 0; i < 8; ++i) acc[i] = 0.f;

    // prologue: stage chunk 0 -> buf 0; bases for its l1
    stage(cl1[0], cm[0], 0);
    loadbase(cl1[0]);
    int curl1 = cl1[0];
    __syncthreads();   // buf 0 ready

#pragma unroll
    for (int d = 0; d < 4; ++d) {
        if (d < 3) stage(cl1[d + 1], cm[d + 1], (d + 1) & 1);  // async DMA
        if (cl1[d] != curl1) { loadbase(cl1[d]); curl1 = cl1[d]; }
        const float* T = Tl + (d & 1) * TBLP;
        const int jl = cjl[d];
        const size_t mrow = (size_t)cm[d] * BB;
        if (jl == 0) {
#pragma unroll
            for (int i = 0; i < 8; ++i) {
                const uint2 u = seqC[mrow + i * QT + tid];   // inline, 1 live
#pragma unroll
                for (int j = 0; j < 8; ++j) {
                    const unsigned w = (j < 4) ? u.x : u.y;
                    const int s2 = (w >> ((j & 3) * 8)) & 0xFF;
                    acc[i] += T[j * 400 + basev[i] + s2];
                }
            }
        } else {            // ragged first chunk of a row (uniform jl)
#pragma unroll
            for (int i = 0; i < 8; ++i) {
                const uint2 u = seqC[mrow + i * QT + tid];
#pragma unroll
                for (int j = 0; j < 8; ++j) {
                    const unsigned w = (j < 4) ? u.x : u.y;
                    const int s2 = (w >> ((j & 3) * 8)) & 0xFF;
                    const float v = T[j * 400 + basev[i] + s2];
                    acc[i] += (j >= jl) ? v : 0.f;
                }
            }
        }
        __syncthreads();    // gathers done + next buffer's DMA drained
    }

    if (MODE == 0) {
        float* row = part + (size_t)blk * BB;
#pragma unroll
        for (int i = 0; i < 8; ++i) row[i * QT + tid] = acc[i];
    } else {
#pragma unroll
        for (int i = 0; i < 8; ++i) atomicAdd(&out[i * QT + tid], acc[i]);
    }
}

// ---------------- Kernel 3: reduce partial rows into out -------------------
// grid (4, 8): x -> 256 float4 of out, y -> 131 part rows each. 8 atomics/word.
__global__ __launch_bounds__(256) void k_reduce(
    const float4* __restrict__ part4,   // [NBLK][1024]
    float* __restrict__ out)
{
    const int b4 = blockIdx.x * 256 + threadIdx.x;   // < 1024
    const int r0 = blockIdx.y * 131;
    const int r1 = min(r0 + 131, NBLK);
    float4 a = make_float4(0.f, 0.f, 0.f, 0.f);
    for (int r = r0; r < r1; ++r) {
        const float4 p = part4[(size_t)r * 1024 + b4];
        a.x += p.x; a.y += p.y; a.z += p.z; a.w += p.w;
    }
    atomicAdd(&out[b4 * 4 + 0], a.x);
    atomicAdd(&out[b4 * 4 + 1], a.y);
    atomicAdd(&out[b4 * 4 + 2], a.z);
    atomicAdd(&out[b4 * 4 + 3], a.w);
}

extern "C" void kernel_launch(void* const* d_in, const int* in_sizes, int n_in,
                              void* d_out, int out_size, void* d_ws, size_t ws_size,
                              hipStream_t stream) {
    const float* x_lc       = (const float*)d_in[0];
    const float* theta_0    = (const float*)d_in[1];
    const float* theta_lc   = (const float*)d_in[2];
    const float* theta_lclc = (const float*)d_in[3];
    // d_in[4] = mask (bool) — implicit: we only iterate l2 > l1.
    float* out = (float*)d_out;

    unsigned char* seqC = (unsigned char*)d_ws;            // 1 MB
    float* part = (float*)((char*)d_ws + (1 << 20));       // 17.2 MB
    const size_t need = (1 << 20) + (size_t)NBLK * BB * 4;

    k_prepare<<<dim3(BB), dim3(256), 0, stream>>>(x_lc, theta_0, theta_lc, seqC, out);
    if (ws_size >= need) {
        k_quad<0><<<dim3(NBLK), dim3(QT), 0, stream>>>(
            theta_lclc, (const uint2*)seqC, part, out);
        k_reduce<<<dim3(4, 8), dim3(256), 0, stream>>>(
            (const float4*)part, out);
    } else {
        k_quad<1><<<dim3(NBLK), dim3(QT), 0, stream>>>(
            theta_lclc, (const uint2*)seqC, part, out);
    }
}

// Round 12
// 91.240 us; speedup vs baseline: 2.7278x; 1.0188x over previous
//
#include <hip/hip_runtime.h>

#define LPOS 256
#define CCH 20
#define BB 4096
#define LC 5120   // LPOS*CCH

// seqC layout: uint2[32][4096] — entry (mw, b) holds bytes s(b, l=8mw..8mw+7).

// ---------------- Kernel 1: seq extraction + linear term -------------------
__global__ __launch_bounds__(256) void k_prepare(
    const float* __restrict__ x_lc, const float* __restrict__ theta_0,
    const float* __restrict__ theta_lc, unsigned char* __restrict__ seqC,
    float* __restrict__ out)
{
    const int b = blockIdx.x;
    const int l = threadIdx.x;
    const float* xp = x_lc + (size_t)b * LC + (size_t)l * CCH;
    const float4* xp4 = reinterpret_cast<const float4*>(xp);
    float v[CCH];
#pragma unroll
    for (int q = 0; q < 5; ++q) {
        float4 t = xp4[q];
        v[q * 4 + 0] = t.x; v[q * 4 + 1] = t.y;
        v[q * 4 + 2] = t.z; v[q * 4 + 3] = t.w;
    }
    int s = 0; float best = v[0];
#pragma unroll
    for (int c = 1; c < CCH; ++c) { if (v[c] > best) { best = v[c]; s = c; } }

    seqC[((size_t)(l >> 3) * BB + b) * 8 + (l & 7)] = (unsigned char)s;

    float lin = theta_lc[l * CCH + s];
#pragma unroll
    for (int off = 32; off > 0; off >>= 1) lin += __shfl_down(lin, off, 64);
    __shared__ float partial[4];
    const int wave = threadIdx.x >> 6;
    const int lane = threadIdx.x & 63;
    if (lane == 0) partial[wave] = lin;
    __syncthreads();
    if (threadIdx.x == 0)
        out[b] = theta_0[0] + partial[0] + partial[1] + partial[2] + partial[3];
}

// ---------------- Kernel 2: masked pairwise quadratic form -----------------
// quad[b] = sum_{l1<l2} Theta[l1,s1,l2,s2]. Flat chunk list (4192 8-wide
// l2-chunks = 1048 blocks x 4, exactly uniform). ALL 4 chunk tables
// (4 x 8x20x20 f32 = 53.2 KB, 3 blocks/CU) staged up front via
// global_load_lds (52 segments), then ONE barrier, then 256 gathers/thread
// with no further syncs/drains — pure LDS-pipe phase.
#define QT 512
#define NMC 32                // 8-wide chunks per row
#define NQUADS 800            // 3200 f32 / 4
#define SEGS 13               // 13 x 1KB wave segments (last 1/4 pad)
#define TBLP (SEGS * 256)     // 3328 f32 (13312 B) per slot
#define NCHT 4192             // total chunks
#define NBLK (NCHT / 4)       // 1048

template <int MODE>
__global__ __launch_bounds__(QT, 6) void k_quad(
    const float* __restrict__ Theta,          // (5120, 5120) f32 row-major
    const uint2* __restrict__ seqC,           // [32][4096]
    float* __restrict__ part,                 // [NBLK][4096] (MODE 0)
    float* __restrict__ out)                  // (MODE 1)
{
    __shared__ float Tl[4 * TBLP];   // 53248 B -> 3 blocks/CU (159.7 KB)

    const int blk = blockIdx.x;
    const int tid = threadIdx.x;
    const int wave = tid >> 6;
    const int lane = tid & 63;

    // ---- locate this block's 4 chunks in the flat list (scalar walk) ----
    int cl1[4], cm[4], cjl[4];
    {
        int T = blk * 4, l1 = 0;
        for (; l1 < 255; ++l1) {
            const int cnt = NMC - ((l1 + 1) >> 3);
            if (T < cnt) break;
            T -= cnt;
        }
        int m = ((l1 + 1) >> 3) + T;
#pragma unroll
        for (int d = 0; d < 4; ++d) {
            cl1[d] = l1; cm[d] = m;
            cjl[d] = (m == ((l1 + 1) >> 3)) ? ((l1 + 1) & 7) : 0;
            ++m;
            if (m == NMC) { ++l1; m = (l1 + 1) >> 3; }
        }
    }

    // Stage chunk (l1, m) into slot: quad u = seg*64+lane -> elems 4u..4u+3;
    // r = u/5 (= j*20+s1), cc = u%5 -> Theta row l1*20+s1,
    // cols (8m+j)*20 + 4cc..+3. u>799 clamped (lands in LDS pad).
    auto stage = [&](int l1, int m, int slot) {
#pragma unroll
        for (int k = 0; k < 2; ++k) {
            const int seg = wave + 8 * k;
            if (seg < SEGS) {
                const int u0 = seg * 64 + lane;
                const int u = (u0 < NQUADS) ? u0 : (NQUADS - 1);
                const int r = u / 5, cc = u - r * 5;
                const int j = r / CCH, s1 = r - j * CCH;
                const float* gp = Theta + (size_t)(l1 * CCH + s1) * LC
                                        + (m * 8 + j) * CCH + cc * 4;
                float* lp = Tl + slot * TBLP + seg * 256;
                __builtin_amdgcn_global_load_lds(
                    (const __attribute__((address_space(1))) void*)gp,
                    (__attribute__((address_space(3))) void*)lp, 16, 0, 0);
            }
        }
    };
    // basev[i] = s1(b_i, l1) * 20 from byte (l1&7) of seqC[l1>>3][b_i]
    int basev[8];
    auto loadbase = [&](int l1) {
        const int mw = l1 >> 3;
        const int wsel = (l1 >> 2) & 1;
        const int sh = (l1 & 3) * 8;
#pragma unroll
        for (int i = 0; i < 8; ++i) {
            const uint2 u = seqC[(size_t)mw * BB + i * QT + tid];
            const unsigned w = wsel ? u.y : u.x;
            basev[i] = (int)((w >> sh) & 0xFFu) * CCH;
        }
    };

    // ---- stage ALL FOUR chunk tables, then one barrier ----
#pragma unroll
    for (int d = 0; d < 4; ++d) stage(cl1[d], cm[d], d);
    loadbase(cl1[0]);                 // hidden under the DMA drain
    int curl1 = cl1[0];
    __syncthreads();                  // single drain for the whole block

    float acc[8];
#pragma unroll
    for (int i = 0; i < 8; ++i) acc[i] = 0.f;

#pragma unroll
    for (int d = 0; d < 4; ++d) {
        if (cl1[d] != curl1) { loadbase(cl1[d]); curl1 = cl1[d]; }
        const float* T = Tl + d * TBLP;
        const int jl = cjl[d];
        const size_t mrow = (size_t)cm[d] * BB;
        if (jl == 0) {
#pragma unroll
            for (int i = 0; i < 8; ++i) {
                const uint2 u = seqC[mrow + i * QT + tid];   // inline, 1 live
#pragma unroll
                for (int j = 0; j < 8; ++j) {
                    const unsigned w = (j < 4) ? u.x : u.y;
                    const int s2 = (w >> ((j & 3) * 8)) & 0xFF;
                    acc[i] += T[j * 400 + basev[i] + s2];
                }
            }
        } else {            // ragged first chunk of a row (uniform jl)
#pragma unroll
            for (int i = 0; i < 8; ++i) {
                const uint2 u = seqC[mrow + i * QT + tid];
#pragma unroll
                for (int j = 0; j < 8; ++j) {
                    const unsigned w = (j < 4) ? u.x : u.y;
                    const int s2 = (w >> ((j & 3) * 8)) & 0xFF;
                    const float v = T[j * 400 + basev[i] + s2];
                    acc[i] += (j >= jl) ? v : 0.f;
                }
            }
        }
    }

    if (MODE == 0) {
        float* row = part + (size_t)blk * BB;
#pragma unroll
        for (int i = 0; i < 8; ++i) row[i * QT + tid] = acc[i];
    } else {
#pragma unroll
        for (int i = 0; i < 8; ++i) atomicAdd(&out[i * QT + tid], acc[i]);
    }
}

// ---------------- Kernel 3: reduce partial rows into out -------------------
// grid (4, 8): x -> 256 float4 of out, y -> 131 part rows each. 8 atomics/word.
__global__ __launch_bounds__(256) void k_reduce(
    const float4* __restrict__ part4,   // [NBLK][1024]
    float* __restrict__ out)
{
    const int b4 = blockIdx.x * 256 + threadIdx.x;   // < 1024
    const int r0 = blockIdx.y * 131;
    const int r1 = min(r0 + 131, NBLK);
    float4 a = make_float4(0.f, 0.f, 0.f, 0.f);
    for (int r = r0; r < r1; ++r) {
        const float4 p = part4[(size_t)r * 1024 + b4];
        a.x += p.x; a.y += p.y; a.z += p.z; a.w += p.w;
    }
    atomicAdd(&out[b4 * 4 + 0], a.x);
    atomicAdd(&out[b4 * 4 + 1], a.y);
    atomicAdd(&out[b4 * 4 + 2], a.z);
    atomicAdd(&out[b4 * 4 + 3], a.w);
}

extern "C" void kernel_launch(void* const* d_in, const int* in_sizes, int n_in,
                              void* d_out, int out_size, void* d_ws, size_t ws_size,
                              hipStream_t stream) {
    const float* x_lc       = (const float*)d_in[0];
    const float* theta_0    = (const float*)d_in[1];
    const float* theta_lc   = (const float*)d_in[2];
    const float* theta_lclc = (const float*)d_in[3];
    // d_in[4] = mask (bool) — implicit: we only iterate l2 > l1.
    float* out = (float*)d_out;

    unsigned char* seqC = (unsigned char*)d_ws;            // 1 MB
    float* part = (float*)((char*)d_ws + (1 << 20));       // 17.2 MB
    const size_t need = (1 << 20) + (size_t)NBLK * BB * 4;

    k_prepare<<<dim3(BB), dim3(256), 0, stream>>>(x_lc, theta_0, theta_lc, seqC, out);
    if (ws_size >= need) {
        k_quad<0><<<dim3(NBLK), dim3(QT), 0, stream>>>(
            theta_lclc, (const uint2*)seqC, part, out);
        k_reduce<<<dim3(4, 8), dim3(256), 0, stream>>>(
            (const float4*)part, out);
    } else {
        k_quad<1><<<dim3(NBLK), dim3(QT), 0, stream>>>(
            theta_lclc, (const uint2*)seqC, part, out);
    }
}

// Round 14
// 71.517 us; speedup vs baseline: 3.4801x; 1.2758x over previous
//
#include <hip/hip_runtime.h>

#define LPOS 256
#define CCH 20
#define BB 4096
#define LC 5120   // LPOS*CCH

// seqC layout: uint4[16][4096] — entry (mw, b) holds bytes s(b, l=16mw..16mw+15).

// ---------------- Kernel 1: seq extraction + linear term -------------------
__global__ __launch_bounds__(256) void k_prepare(
    const float* __restrict__ x_lc, const float* __restrict__ theta_0,
    const float* __restrict__ theta_lc, unsigned char* __restrict__ seqC,
    float* __restrict__ out)
{
    const int b = blockIdx.x;
    const int l = threadIdx.x;
    const float* xp = x_lc + (size_t)b * LC + (size_t)l * CCH;
    const float4* xp4 = reinterpret_cast<const float4*>(xp);
    float v[CCH];
#pragma unroll
    for (int q = 0; q < 5; ++q) {
        float4 t = xp4[q];
        v[q * 4 + 0] = t.x; v[q * 4 + 1] = t.y;
        v[q * 4 + 2] = t.z; v[q * 4 + 3] = t.w;
    }
    int s = 0; float best = v[0];
#pragma unroll
    for (int c = 1; c < CCH; ++c) { if (v[c] > best) { best = v[c]; s = c; } }

    seqC[(size_t)(l >> 4) * (BB * 16) + (size_t)b * 16 + (l & 15)] =
        (unsigned char)s;

    float lin = theta_lc[l * CCH + s];
#pragma unroll
    for (int off = 32; off > 0; off >>= 1) lin += __shfl_down(lin, off, 64);
    __shared__ float partial[4];
    const int wave = threadIdx.x >> 6;
    const int lane = threadIdx.x & 63;
    if (lane == 0) partial[wave] = lin;
    __syncthreads();
    if (threadIdx.x == 0)
        out[b] = theta_0[0] + partial[0] + partial[1] + partial[2] + partial[3];
}

// ---------------- Kernel 2: masked pairwise quadratic form -----------------
// quad[b] = sum_{l1<l2} Theta[l1,s1,l2,s2]. Flat list of 16-wide l2-chunks:
// total = sum_{l1}(16 - ((l1+1)>>4)) = 2160 = 720 blocks x 3 chunks
// (EXACTLY uniform; 720 resident blocks => single dispatch generation;
// R13 bug: claimed 1936 total and dropped 224 chunks).
// Per chunk: 16x20x20 f32 table (25.6 KB = exactly 25 1KB gload_lds
// segments) staged once, then all 4096 batches gathered (thread t: batches
// i*512+t, i<8; 128 gathers/thread/chunk). 5 barriers per block total.
#define QT 512
#define TBL 6400              // 16*20*20 f32 = 25600 B, 1600 quads, 25 segs
#define NCHT 2160             // total 16-wide chunks
#define CPB 3                 // chunks per block
#define NBLK (NCHT / CPB)     // 720

template <int MODE>
__global__ __launch_bounds__(QT, 8) void k_quad(
    const float* __restrict__ Theta,          // (5120, 5120) f32 row-major
    const uint4* __restrict__ seqC,           // [16][4096]
    float* __restrict__ part,                 // [NBLK][4096] (MODE 0)
    float* __restrict__ out)                  // (MODE 1)
{
    __shared__ float Tl[TBL];    // 25.6 KB -> 4 blocks/CU cap (102.4 KB)

    const int blk = blockIdx.x;
    const int tid = threadIdx.x;
    const int wave = tid >> 6;
    const int lane = tid & 63;

    // ---- locate this block's 3 chunks in the flat list (scalar walk) ----
    int cl1[CPB], cm[CPB], cjl[CPB];
    {
        int T = blk * CPB, l1 = 0;
        for (; l1 < 255; ++l1) {
            const int cnt = 16 - ((l1 + 1) >> 4);
            if (T < cnt) break;
            T -= cnt;
        }
        int m = ((l1 + 1) >> 4) + T;
#pragma unroll
        for (int d = 0; d < CPB; ++d) {
            cl1[d] = l1; cm[d] = m;
            cjl[d] = (m == ((l1 + 1) >> 4)) ? ((l1 + 1) & 15) : 0;
            ++m;
            if (m == 16) { ++l1; m = (l1 + 1) >> 4; }
        }
    }

    // Stage chunk (l1, m): quad u = seg*64+lane (< 1600 exactly) -> elems
    // 4u..4u+3; r = u/5 (= j*20+s1), cc = u%5 -> Theta row l1*20+s1,
    // cols (16m+j)*20 + 4cc..+3 (16B-aligned, in-row).
    auto stage = [&](int l1, int m) {
#pragma unroll
        for (int k = 0; k < 4; ++k) {
            const int seg = wave + 8 * k;
            if (seg < 25) {
                const int u = seg * 64 + lane;
                const int r = u / 5, cc = u - r * 5;
                const int j = r / CCH, s1 = r - j * CCH;
                const float* gp = Theta + (size_t)(l1 * CCH + s1) * LC
                                        + (m * 16 + j) * CCH + cc * 4;
                float* lp = Tl + seg * 256;
                __builtin_amdgcn_global_load_lds(
                    (const __attribute__((address_space(1))) void*)gp,
                    (__attribute__((address_space(3))) void*)lp, 16, 0, 0);
            }
        }
    };
    // basev[i] = s1(b_i, l1) * 20 from byte (l1&15) of seqC[l1>>4][b_i]
    int basev[8];
    auto loadbase = [&](int l1) {
        const int mw = l1 >> 4;
        const int wsel = (l1 >> 2) & 3;
        const int sh = (l1 & 3) * 8;
#pragma unroll
        for (int i = 0; i < 8; ++i) {
            const uint4 u = seqC[(size_t)mw * BB + i * QT + tid];
            const unsigned w = (wsel == 0) ? u.x : (wsel == 1) ? u.y
                             : (wsel == 2) ? u.z : u.w;
            basev[i] = (int)((w >> sh) & 0xFFu) * CCH;
        }
    };

    float acc[8];
#pragma unroll
    for (int i = 0; i < 8; ++i) acc[i] = 0.f;

    // gather one chunk d from the table
    auto gather = [&](int d) {
        const int jl = cjl[d];
        const size_t mrow = (size_t)cm[d] * BB;
        if (jl == 0) {
#pragma unroll
            for (int i = 0; i < 8; ++i) {
                const uint4 u = seqC[mrow + i * QT + tid];   // inline, 1 live
#pragma unroll
                for (int j = 0; j < 16; ++j) {
                    const unsigned w = (j < 4) ? u.x : (j < 8) ? u.y
                                     : (j < 12) ? u.z : u.w;
                    const int s2 = (w >> ((j & 3) * 8)) & 0xFF;
                    acc[i] += Tl[j * 400 + basev[i] + s2];
                }
            }
        } else {            // ragged first chunk of a row (uniform jl)
#pragma unroll
            for (int i = 0; i < 8; ++i) {
                const uint4 u = seqC[mrow + i * QT + tid];
#pragma unroll
                for (int j = 0; j < 16; ++j) {
                    const unsigned w = (j < 4) ? u.x : (j < 8) ? u.y
                                     : (j < 12) ? u.z : u.w;
                    const int s2 = (w >> ((j & 3) * 8)) & 0xFF;
                    const float v = Tl[j * 400 + basev[i] + s2];
                    acc[i] += (j >= jl) ? v : 0.f;
                }
            }
        }
    };

    int curl1 = cl1[0];
    stage(cl1[0], cm[0]);
    loadbase(cl1[0]);
    __syncthreads();            // table 0 ready
    gather(0);
#pragma unroll
    for (int d = 1; d < CPB; ++d) {
        __syncthreads();        // WAR: all reads done before restage
        stage(cl1[d], cm[d]);
        if (cl1[d] != curl1) { loadbase(cl1[d]); curl1 = cl1[d]; }
        __syncthreads();        // table d ready
        gather(d);
    }

    if (MODE == 0) {
        float* row = part + (size_t)blk * BB;
#pragma unroll
        for (int i = 0; i < 8; ++i) row[i * QT + tid] = acc[i];
    } else {
#pragma unroll
        for (int i = 0; i < 8; ++i) atomicAdd(&out[i * QT + tid], acc[i]);
    }
}

// ---------------- Kernel 3: reduce partial rows into out -------------------
// grid (4, 45): x -> 256 float4-columns of out, y -> 16 part rows each.
// 180 blocks; 45 atomics per out word.
__global__ __launch_bounds__(256) void k_reduce(
    const float4* __restrict__ part4,   // [NBLK][1024]
    float* __restrict__ out)
{
    const int b4 = blockIdx.x * 256 + threadIdx.x;   // < 1024
    const int r0 = blockIdx.y * 16;
    const int r1 = min(r0 + 16, NBLK);
    float4 a = make_float4(0.f, 0.f, 0.f, 0.f);
    for (int r = r0; r < r1; ++r) {
        const float4 p = part4[(size_t)r * 1024 + b4];
        a.x += p.x; a.y += p.y; a.z += p.z; a.w += p.w;
    }
    atomicAdd(&out[b4 * 4 + 0], a.x);
    atomicAdd(&out[b4 * 4 + 1], a.y);
    atomicAdd(&out[b4 * 4 + 2], a.z);
    atomicAdd(&out[b4 * 4 + 3], a.w);
}

extern "C" void kernel_launch(void* const* d_in, const int* in_sizes, int n_in,
                              void* d_out, int out_size, void* d_ws, size_t ws_size,
                              hipStream_t stream) {
    const float* x_lc       = (const float*)d_in[0];
    const float* theta_0    = (const float*)d_in[1];
    const float* theta_lc   = (const float*)d_in[2];
    const float* theta_lclc = (const float*)d_in[3];
    // d_in[4] = mask (bool) — implicit: we only iterate l2 > l1.
    float* out = (float*)d_out;

    unsigned char* seqC = (unsigned char*)d_ws;            // 1 MB
    float* part = (float*)((char*)d_ws + (1 << 20));       // 11.8 MB
    const size_t need = (1 << 20) + (size_t)NBLK * BB * 4;

    k_prepare<<<dim3(BB), dim3(256), 0, stream>>>(x_lc, theta_0, theta_lc, seqC, out);
    if (ws_size >= need) {
        k_quad<0><<<dim3(NBLK), dim3(QT), 0, stream>>>(
            theta_lclc, (const uint4*)seqC, part, out);
        k_reduce<<<dim3(4, 45), dim3(256), 0, stream>>>(
            (const float4*)part, out);
    } else {
        k_quad<1><<<dim3(NBLK), dim3(QT), 0, stream>>>(
            theta_lclc, (const uint4*)seqC, part, out);
    }
}

// Round 15
// 70.592 us; speedup vs baseline: 3.5257x; 1.0131x over previous
//
#include <hip/hip_runtime.h>

#define LPOS 256
#define CCH 20
#define BB 4096
#define LC 5120   // LPOS*CCH

// seqC layout: uint4[16][4096] — entry (mw, b) holds bytes s(b, l=16mw..16mw+15).

// ---------------- Kernel 1: seq extraction + linear term -------------------
__global__ __launch_bounds__(256) void k_prepare(
    const float* __restrict__ x_lc, const float* __restrict__ theta_0,
    const float* __restrict__ theta_lc, unsigned char* __restrict__ seqC,
    float* __restrict__ out)
{
    const int b = blockIdx.x;
    const int l = threadIdx.x;
    const float* xp = x_lc + (size_t)b * LC + (size_t)l * CCH;
    const float4* xp4 = reinterpret_cast<const float4*>(xp);
    float v[CCH];
#pragma unroll
    for (int q = 0; q < 5; ++q) {
        float4 t = xp4[q];
        v[q * 4 + 0] = t.x; v[q * 4 + 1] = t.y;
        v[q * 4 + 2] = t.z; v[q * 4 + 3] = t.w;
    }
    int s = 0; float best = v[0];
#pragma unroll
    for (int c = 1; c < CCH; ++c) { if (v[c] > best) { best = v[c]; s = c; } }

    seqC[(size_t)(l >> 4) * (BB * 16) + (size_t)b * 16 + (l & 15)] =
        (unsigned char)s;

    float lin = theta_lc[l * CCH + s];
#pragma unroll
    for (int off = 32; off > 0; off >>= 1) lin += __shfl_down(lin, off, 64);
    __shared__ float partial[4];
    const int wave = threadIdx.x >> 6;
    const int lane = threadIdx.x & 63;
    if (lane == 0) partial[wave] = lin;
    __syncthreads();
    if (threadIdx.x == 0)
        out[b] = theta_0[0] + partial[0] + partial[1] + partial[2] + partial[3];
}

// ---------------- Kernel 2: masked pairwise quadratic form -----------------
// quad[b] = sum_{l1<l2} Theta[l1,s1,l2,s2]. Flat list of 2160 16-wide
// l2-chunks distributed over EXACTLY 1024 blocks (= 4 blocks/CU x 8 waves,
// full residency, single dispatch generation — R14 lesson: 720 blocks left
// 30% of wave slots empty and ran latency-bound).
// Blocks 0..111 take 3 chunks, 112..1023 take 2 (112*3 + 912*2 = 2160).
// Consecutive blockIdx -> distinct CUs, so heavy blocks spread: per-CU
// chunk totals 9 vs 8 (+6.6% spread vs mean 8.44).
// Per chunk: 16x20x20 f32 table (25.6 KB = exactly 25 1KB gload_lds
// segments) staged once, then all 4096 batches gathered (thread t: batches
// i*512+t, i<8; 128 gathers/thread/chunk).
#define QT 512
#define TBL 6400              // 16*20*20 f32 = 25600 B, 1600 quads, 25 segs
#define NCHT 2160             // total 16-wide chunks
#define NBLK 1024
#define NHEAVY 112            // blocks with 3 chunks

template <int MODE>
__global__ __launch_bounds__(QT, 8) void k_quad(
    const float* __restrict__ Theta,          // (5120, 5120) f32 row-major
    const uint4* __restrict__ seqC,           // [16][4096]
    float* __restrict__ part,                 // [NBLK][4096] (MODE 0)
    float* __restrict__ out)                  // (MODE 1)
{
    __shared__ float Tl[TBL];    // 25.6 KB -> 4 blocks/CU (102.4 KB)

    const int blk = blockIdx.x;
    const int tid = threadIdx.x;
    const int wave = tid >> 6;
    const int lane = tid & 63;

    const int cnt   = (blk < NHEAVY) ? 3 : 2;
    const int start = (blk < NHEAVY) ? 3 * blk : 3 * NHEAVY + 2 * (blk - NHEAVY);

    // ---- locate chunks [start, start+cnt) in the flat list (scalar walk) --
    int cl1[3], cm[3], cjl[3];
    {
        int T = start, l1 = 0;
        for (; l1 < 255; ++l1) {
            const int c = 16 - ((l1 + 1) >> 4);
            if (T < c) break;
            T -= c;
        }
        int m = ((l1 + 1) >> 4) + T;
#pragma unroll
        for (int d = 0; d < 3; ++d) {          // fill 3; use first cnt
            cl1[d] = l1; cm[d] = m;
            cjl[d] = (m == ((l1 + 1) >> 4)) ? ((l1 + 1) & 15) : 0;
            ++m;
            if (m == 16) { ++l1; m = (l1 + 1) >> 4; }
        }
    }

    // Stage chunk (l1, m): quad u = seg*64+lane (< 1600 exactly) -> elems
    // 4u..4u+3; r = u/5 (= j*20+s1), cc = u%5 -> Theta row l1*20+s1,
    // cols (16m+j)*20 + 4cc..+3 (16B-aligned, in-row).
    auto stage = [&](int l1, int m) {
#pragma unroll
        for (int k = 0; k < 4; ++k) {
            const int seg = wave + 8 * k;
            if (seg < 25) {
                const int u = seg * 64 + lane;
                const int r = u / 5, cc = u - r * 5;
                const int j = r / CCH, s1 = r - j * CCH;
                const float* gp = Theta + (size_t)(l1 * CCH + s1) * LC
                                        + (m * 16 + j) * CCH + cc * 4;
                float* lp = Tl + seg * 256;
                __builtin_amdgcn_global_load_lds(
                    (const __attribute__((address_space(1))) void*)gp,
                    (__attribute__((address_space(3))) void*)lp, 16, 0, 0);
            }
        }
    };
    // basev[i] = s1(b_i, l1) * 20 from byte (l1&15) of seqC[l1>>4][b_i]
    int basev[8];
    auto loadbase = [&](int l1) {
        const int mw = l1 >> 4;
        const int wsel = (l1 >> 2) & 3;
        const int sh = (l1 & 3) * 8;
#pragma unroll
        for (int i = 0; i < 8; ++i) {
            const uint4 u = seqC[(size_t)mw * BB + i * QT + tid];
            const unsigned w = (wsel == 0) ? u.x : (wsel == 1) ? u.y
                             : (wsel == 2) ? u.z : u.w;
            basev[i] = (int)((w >> sh) & 0xFFu) * CCH;
        }
    };

    float acc[8];
#pragma unroll
    for (int i = 0; i < 8; ++i) acc[i] = 0.f;

    // gather one chunk d from the table
    auto gather = [&](int d) {
        const int jl = cjl[d];
        const size_t mrow = (size_t)cm[d] * BB;
        if (jl == 0) {
#pragma unroll
            for (int i = 0; i < 8; ++i) {
                const uint4 u = seqC[mrow + i * QT + tid];   // inline, 1 live
#pragma unroll
                for (int j = 0; j < 16; ++j) {
                    const unsigned w = (j < 4) ? u.x : (j < 8) ? u.y
                                     : (j < 12) ? u.z : u.w;
                    const int s2 = (w >> ((j & 3) * 8)) & 0xFF;
                    acc[i] += Tl[j * 400 + basev[i] + s2];
                }
            }
        } else {            // ragged first chunk of a row (uniform jl)
#pragma unroll
            for (int i = 0; i < 8; ++i) {
                const uint4 u = seqC[mrow + i * QT + tid];
#pragma unroll
                for (int j = 0; j < 16; ++j) {
                    const unsigned w = (j < 4) ? u.x : (j < 8) ? u.y
                                     : (j < 12) ? u.z : u.w;
                    const int s2 = (w >> ((j & 3) * 8)) & 0xFF;
                    const float v = Tl[j * 400 + basev[i] + s2];
                    acc[i] += (j >= jl) ? v : 0.f;
                }
            }
        }
    };

    int curl1 = cl1[0];
    stage(cl1[0], cm[0]);
    loadbase(cl1[0]);
    __syncthreads();            // table 0 ready
    gather(0);
    for (int d = 1; d < cnt; ++d) {    // cnt is block-uniform
        __syncthreads();        // WAR: all reads done before restage
        stage(cl1[d], cm[d]);
        if (cl1[d] != curl1) { loadbase(cl1[d]); curl1 = cl1[d]; }
        __syncthreads();        // table d ready
        gather(d);
    }

    if (MODE == 0) {
        float* row = part + (size_t)blk * BB;
#pragma unroll
        for (int i = 0; i < 8; ++i) row[i * QT + tid] = acc[i];
    } else {
#pragma unroll
        for (int i = 0; i < 8; ++i) atomicAdd(&out[i * QT + tid], acc[i]);
    }
}

// ---------------- Kernel 3: reduce partial rows into out -------------------
// grid (4, 64): x -> 256 float4-columns of out, y -> 16 part rows each.
// 256 blocks; 64 atomics per out word.
__global__ __launch_bounds__(256) void k_reduce(
    const float4* __restrict__ part4,   // [NBLK][1024]
    float* __restrict__ out)
{
    const int b4 = blockIdx.x * 256 + threadIdx.x;   // < 1024
    const int r0 = blockIdx.y * 16;
    float4 a = make_float4(0.f, 0.f, 0.f, 0.f);
    for (int r = r0; r < r0 + 16; ++r) {
        const float4 p = part4[(size_t)r * 1024 + b4];
        a.x += p.x; a.y += p.y; a.z += p.z; a.w += p.w;
    }
    atomicAdd(&out[b4 * 4 + 0], a.x);
    atomicAdd(&out[b4 * 4 + 1], a.y);
    atomicAdd(&out[b4 * 4 + 2], a.z);
    atomicAdd(&out[b4 * 4 + 3], a.w);
}

extern "C" void kernel_launch(void* const* d_in, const int* in_sizes, int n_in,
                              void* d_out, int out_size, void* d_ws, size_t ws_size,
                              hipStream_t stream) {
    const float* x_lc       = (const float*)d_in[0];
    const float* theta_0    = (const float*)d_in[1];
    const float* theta_lc   = (const float*)d_in[2];
    const float* theta_lclc = (const float*)d_in[3];
    // d_in[4] = mask (bool) — implicit: we only iterate l2 > l1.
    float* out = (float*)d_out;

    unsigned char* seqC = (unsigned char*)d_ws;            // 1 MB
    float* part = (float*)((char*)d_ws + (1 << 20));       // 16.8 MB
    const size_t need = (1 << 20) + (size_t)NBLK * BB * 4;

    k_prepare<<<dim3(BB), dim3(256), 0, stream>>>(x_lc, theta_0, theta_lc, seqC, out);
    if (ws_size >= need) {
        k_quad<0><<<dim3(NBLK), dim3(QT), 0, stream>>>(
            theta_lclc, (const uint4*)seqC, part, out);
        k_reduce<<<dim3(4, 64), dim3(256), 0, stream>>>(
            (const float4*)part, out);
    } else {
        k_quad<1><<<dim3(NBLK), dim3(QT), 0, stream>>>(
            theta_lclc, (const uint4*)seqC, part, out);
    }
}